// Round 1
// baseline (2553.924 us; speedup 1.0000x reference)
//
#include <hip/hip_runtime.h>

#define N_NODES 50000
#define N_EDGES 800000
#define N_GRAPHS 256

// ---------------------------------------------------------------------------
// scatter: agg[dst][j] += src_data[src][j] * w   (flat grid-stride over E*d)
// d = 1<<dlog; src rows have stride src_stride (lets us scatter a column slice)
// ---------------------------------------------------------------------------
__global__ void scatter_kernel(const float* __restrict__ src_data, int src_stride,
                               const int* __restrict__ ei, const float* __restrict__ ew,
                               float* __restrict__ agg, int dlog)
{
    const int d = 1 << dlog;
    const long total = (long)N_EDGES << dlog;
    const long gsz = (long)gridDim.x * blockDim.x;
    for (long i = (long)blockIdx.x * blockDim.x + threadIdx.x; i < total; i += gsz) {
        const int e = (int)(i >> dlog);
        const int j = (int)(i & (d - 1));
        const int s = ei[e];             // src node
        const int t = ei[N_EDGES + e];   // dst node
        const float w = ew[e];
        atomicAdd(&agg[(long)t * d + j], src_data[(long)s * src_stride + j] * w);
    }
}

// ---------------------------------------------------------------------------
// conv epilogue: out[n][c] = tanh(agg[n][:] @ Wr[c][:] + b[c] + xr[n][:] @ Wroot[c][:])
// OUT in {128}; 256 threads/block -> ROWS=2 rows per block
// ---------------------------------------------------------------------------
template<int K, int OUT>
__global__ void conv_post_kernel(const float* __restrict__ agg, const float* __restrict__ xr,
                                 const float* __restrict__ Wr, const float* __restrict__ b,
                                 const float* __restrict__ Wroot, float* __restrict__ out)
{
    constexpr int ROWS = 256 / OUT;
    const int c = threadIdx.x % OUT;
    const int r = threadIdx.x / OUT;
    const int n = blockIdx.x * ROWS + r;
    if (n >= N_NODES) return;
    const float* __restrict__ a  = agg + (long)n * K;
    const float* __restrict__ x  = xr  + (long)n * K;
    const float* __restrict__ wr = Wr    + (long)c * K;
    const float* __restrict__ wt = Wroot + (long)c * K;
    float acc = b[c];
#pragma unroll 8
    for (int k = 0; k < K; ++k) acc = fmaf(a[k], wr[k], acc);
#pragma unroll 8
    for (int k = 0; k < K; ++k) acc = fmaf(x[k], wt[k], acc);
    out[(long)n * OUT + c] = tanhf(acc);
}

// ---------------------------------------------------------------------------
// layer-3 pre-transform: yr[n][0:64]  = h2[n] @ W3r.T        (to be scattered)
//                        yr[n][64:128]= h2[n] @ W3root.T + b3 (root path)
// ---------------------------------------------------------------------------
__global__ void layer3_pre_kernel(const float* __restrict__ h2,
                                  const float* __restrict__ W3r, const float* __restrict__ b3,
                                  const float* __restrict__ W3root,
                                  float* __restrict__ yr)
{
    const int c = threadIdx.x & 127;
    const int r = threadIdx.x >> 7;
    const int n = blockIdx.x * 2 + r;
    if (n >= N_NODES) return;
    const float* w;
    float acc;
    if (c < 64) { w = W3r + (long)c * 128;         acc = 0.f; }
    else        { w = W3root + (long)(c - 64) * 128; acc = b3[c - 64]; }
    const float* h = h2 + (long)n * 128;
#pragma unroll 8
    for (int k = 0; k < 128; ++k) acc = fmaf(h[k], w[k], acc);
    yr[(long)n * 128 + c] = acc;
}

// ---------------------------------------------------------------------------
// h3 = tanh(agg3 + r3); pool: g[batch[n]][c] += h3[n][c]
// ---------------------------------------------------------------------------
__global__ void pool_kernel(const float* __restrict__ agg3, const float* __restrict__ yr,
                            const int* __restrict__ batch, float* __restrict__ g)
{
    const long total = (long)N_NODES * 64;
    const long gsz = (long)gridDim.x * blockDim.x;
    for (long i = (long)blockIdx.x * blockDim.x + threadIdx.x; i < total; i += gsz) {
        const int n = (int)(i >> 6);
        const int c = (int)(i & 63);
        const float v = tanhf(agg3[(long)n * 64 + c] + yr[(long)n * 128 + 64 + c]);
        atomicAdd(&g[batch[n] * 64 + c], v);
    }
}

// ---------------------------------------------------------------------------
// tiny MLP: 64 -> 32 -> 16 -> 1 per graph; one thread per graph
// ---------------------------------------------------------------------------
__global__ void mlp_kernel(const float* __restrict__ g,
                           const float* __restrict__ Wm1, const float* __restrict__ bm1,
                           const float* __restrict__ Wm2, const float* __restrict__ bm2,
                           const float* __restrict__ Wm3, const float* __restrict__ bm3,
                           float* __restrict__ out)
{
    const int gi = blockIdx.x * blockDim.x + threadIdx.x;
    if (gi >= N_GRAPHS) return;
    const float* gr = g + gi * 64;
    float h1[32];
#pragma unroll
    for (int j = 0; j < 32; ++j) {
        float a = bm1[j];
        const float* w = Wm1 + j * 64;
        for (int k = 0; k < 64; ++k) a = fmaf(gr[k], w[k], a);
        h1[j] = fmaxf(a, 0.f);
    }
    float h2[16];
#pragma unroll
    for (int j = 0; j < 16; ++j) {
        float a = bm2[j];
        const float* w = Wm2 + j * 32;
        for (int k = 0; k < 32; ++k) a = fmaf(h1[k], w[k], a);
        h2[j] = fmaxf(a, 0.f);
    }
    float a = bm3[0];
    for (int k = 0; k < 16; ++k) a = fmaf(h2[k], Wm3[k], a);
    out[gi] = a;
}

extern "C" void kernel_launch(void* const* d_in, const int* in_sizes, int n_in,
                              void* d_out, int out_size, void* d_ws, size_t ws_size,
                              hipStream_t stream) {
    const float* x      = (const float*)d_in[0];
    const int*   ei     = (const int*)  d_in[1];
    const int*   batch  = (const int*)  d_in[2];
    const float* ew     = (const float*)d_in[3];
    const float* W1r    = (const float*)d_in[4];
    const float* b1     = (const float*)d_in[5];
    const float* W1root = (const float*)d_in[6];
    const float* W2r    = (const float*)d_in[7];
    const float* b2     = (const float*)d_in[8];
    const float* W2root = (const float*)d_in[9];
    const float* W3r    = (const float*)d_in[10];
    const float* b3     = (const float*)d_in[11];
    const float* W3root = (const float*)d_in[12];
    const float* Wm1    = (const float*)d_in[13];
    const float* bm1    = (const float*)d_in[14];
    const float* Wm2    = (const float*)d_in[15];
    const float* bm2    = (const float*)d_in[16];
    const float* Wm3    = (const float*)d_in[17];
    const float* bm3    = (const float*)d_in[18];
    float* out = (float*)d_out;

    float* P0   = (float*)d_ws;                 // N*128 floats
    float* P1   = P0 + (long)N_NODES * 128;     // N*128 floats
    float* P2   = P1 + (long)N_NODES * 128;     // N*128 floats
    float* POOL = P2 + (long)N_NODES * 128;     // 256*64 floats

    // ---- layer 1: agg1 (N x 64) in P0; h1 (N x 128) in P1 ----
    hipMemsetAsync(P0, 0, (size_t)N_NODES * 64 * sizeof(float), stream);
    scatter_kernel<<<2048, 256, 0, stream>>>(x, 64, ei, ew, P0, 6);
    conv_post_kernel<64, 128><<<N_NODES / 2, 256, 0, stream>>>(P0, x, W1r, b1, W1root, P1);

    // ---- layer 2: agg2 (N x 128) in P2; h2 (N x 128) in P0 ----
    hipMemsetAsync(P2, 0, (size_t)N_NODES * 128 * sizeof(float), stream);
    scatter_kernel<<<2048, 256, 0, stream>>>(P1, 128, ei, ew, P2, 7);
    conv_post_kernel<128, 128><<<N_NODES / 2, 256, 0, stream>>>(P2, P1, W2r, b2, W2root, P0);

    // ---- layer 3: yr (N x 128: [y3|r3]) in P1; agg3 (N x 64) in P2 ----
    layer3_pre_kernel<<<N_NODES / 2, 256, 0, stream>>>(P0, W3r, b3, W3root, P1);
    hipMemsetAsync(P2, 0, (size_t)N_NODES * 64 * sizeof(float), stream);
    scatter_kernel<<<2048, 256, 0, stream>>>(P1, 128, ei, ew, P2, 6);

    // ---- pool + MLP ----
    hipMemsetAsync(POOL, 0, (size_t)N_GRAPHS * 64 * sizeof(float), stream);
    pool_kernel<<<2048, 256, 0, stream>>>(P2, P1, batch, POOL);
    mlp_kernel<<<1, 256, 0, stream>>>(POOL, Wm1, bm1, Wm2, bm2, Wm3, bm3, out);
}